// Round 1
// baseline (602.562 us; speedup 1.0000x reference)
//
#include <hip/hip_runtime.h>
#include <math.h>

#define B 4
#define C 64
#define H 256
#define W 256
#define HW (H*W)            // 65536
#define CHW (C*HW)          // 4194304
#define BCHW (B*CHW)        // 16777216

// ---------------------------------------------------------------------------
// Kernel 1: qkv = conv1x1(x, w_qkv) + b_qkv  ->  q,k,v each [B,C,H,W] in ws
// ws layout: q at 0, k at BCHW, v at 2*BCHW (floats). scores later alias q.
// ---------------------------------------------------------------------------
__global__ __launch_bounds__(256) void qkv_kernel(
    const float* __restrict__ x, const float* __restrict__ w,
    const float* __restrict__ bias, float* __restrict__ ws)
{
    __shared__ float wl[192 * 64];
    __shared__ float bl[192];
    int t = threadIdx.x;
    for (int i = t; i < 192 * 64; i += 256) wl[i] = w[i];
    if (t < 192) bl[t] = bias[t];
    __syncthreads();

    int p = blockIdx.x * 256 + t;          // pixel id in [0, B*HW)
    int b = p >> 16;
    int s = p & (HW - 1);

    const float* xp = x + (size_t)b * CHW + s;
    float xr[64];
    #pragma unroll
    for (int c = 0; c < 64; ++c) xr[c] = xp[(size_t)c * HW];

    for (int oc = 0; oc < 192; ++oc) {
        float acc = bl[oc];
        const float* wrow = &wl[oc * 64];
        #pragma unroll
        for (int c = 0; c < 64; ++c) acc += wrow[c] * xr[c];
        int grp = oc >> 6, cc = oc & 63;
        ws[(size_t)grp * BCHW + (size_t)b * CHW + (size_t)cc * HW + s] = acc;
    }
}

// ---------------------------------------------------------------------------
// Kernel 2: scores[b,c,h,g] = sum_w q[b,c,h,w]*k[b,c,g,w]
// Block = (b*64+c, h-tile of 64). 256 threads (16x16), 4x16 outputs/thread.
// Writes scores OVER the q region: this block's written rows == the q rows
// only this block reads, and all reads complete before the epilogue store.
// ---------------------------------------------------------------------------
#define WC 16
__global__ __launch_bounds__(256) void scores_kernel(float* __restrict__ ws)
{
    __shared__ float Qt[WC][68];    // transposed [w][h], stride 68 (16B aligned)
    __shared__ float Kt[WC][260];   // transposed [w][g], stride 260 (16B aligned)

    int t  = threadIdx.x;
    int tx = t & 15, ty = t >> 4;
    int bc = blockIdx.x >> 2;            // b*64 + c
    int h0 = (blockIdx.x & 3) * 64;

    const float* qb = ws + (size_t)bc * HW;
    const float* kb = ws + (size_t)BCHW + (size_t)bc * HW;

    float acc[4][16];
    #pragma unroll
    for (int i = 0; i < 4; ++i)
        #pragma unroll
        for (int j = 0; j < 16; ++j) acc[i][j] = 0.f;

    int lc = t & 15;       // w column within chunk
    int lr = t >> 4;       // row base

    for (int wc = 0; wc < 256; wc += WC) {
        __syncthreads();
        // stage Q[h0..h0+63][wc..wc+15] -> Qt[w][h]
        #pragma unroll
        for (int jj = 0; jj < 4; ++jj) {
            int r = lr + 16 * jj;
            Qt[lc][r] = qb[(h0 + r) * 256 + wc + lc];
        }
        // stage K[0..255][wc..wc+15] -> Kt[w][g]
        #pragma unroll
        for (int jj = 0; jj < 16; ++jj) {
            int g = lr + 16 * jj;
            Kt[lc][g] = kb[g * 256 + wc + lc];
        }
        __syncthreads();

        #pragma unroll
        for (int w = 0; w < WC; ++w) {
            float4 a4 = *(const float4*)&Qt[w][ty * 4];
            float av[4] = {a4.x, a4.y, a4.z, a4.w};
            float bvs[16];
            #pragma unroll
            for (int jc = 0; jc < 4; ++jc) {
                float4 b4 = *(const float4*)&Kt[w][jc * 64 + tx * 4];
                bvs[jc*4+0] = b4.x; bvs[jc*4+1] = b4.y;
                bvs[jc*4+2] = b4.z; bvs[jc*4+3] = b4.w;
            }
            #pragma unroll
            for (int i = 0; i < 4; ++i)
                #pragma unroll
                for (int j = 0; j < 16; ++j)
                    acc[i][j] += av[i] * bvs[j];
        }
    }

    // epilogue: write scores over q region
    float* sb = (float*)qb;
    #pragma unroll
    for (int i = 0; i < 4; ++i) {
        int h = h0 + ty * 4 + i;
        #pragma unroll
        for (int jc = 0; jc < 4; ++jc) {
            float4 o = make_float4(acc[i][jc*4+0], acc[i][jc*4+1],
                                   acc[i][jc*4+2], acc[i][jc*4+3]);
            *(float4*)&sb[h * 256 + jc * 64 + tx * 4] = o;
        }
    }
}

// ---------------------------------------------------------------------------
// Kernel 3: attn = softmax(dwconv3x3(scores)+b_dw) ; out = attn@V + x
// Block = (b*64+c, h-tile of 16). 256 threads = one column each.
// ---------------------------------------------------------------------------
#define TH 16
__global__ __launch_bounds__(256) void attn_kernel(
    const float* __restrict__ wsp,      // ws base (scores at 0, v at 2*BCHW)
    const float* __restrict__ wdw, const float* __restrict__ bdw,
    const float* __restrict__ x, float* __restrict__ out)
{
    __shared__ float s_sc[TH + 2][256];   // score rows with halo
    __shared__ float s_at[TH][256];       // exp(logits - max)
    __shared__ float red[TH][4];

    int t  = threadIdx.x;
    int bc = blockIdx.x >> 4;
    int h0 = (blockIdx.x & 15) * TH;
    int c  = bc & 63;

    const float* sb = wsp + (size_t)bc * HW;                     // scores (q alias)
    const float* vb = wsp + (size_t)2 * BCHW + (size_t)bc * HW;  // v slice

    // load 18 score rows (zero pad outside [0,256))
    #pragma unroll
    for (int i = 0; i < TH + 2; ++i) {
        int h = h0 - 1 + i;
        s_sc[i][t] = (h >= 0 && h < 256) ? sb[h * 256 + t] : 0.f;
    }
    __syncthreads();

    float w00 = wdw[c*9+0], w01 = wdw[c*9+1], w02 = wdw[c*9+2];
    float w10 = wdw[c*9+3], w11 = wdw[c*9+4], w12 = wdw[c*9+5];
    float w20 = wdw[c*9+6], w21 = wdw[c*9+7], w22 = wdw[c*9+8];
    float bias = bdw[c];

    float y[TH];
    #pragma unroll
    for (int i = 0; i < TH; ++i) {
        float l0 = (t > 0)   ? s_sc[i  ][t-1] : 0.f;
        float r0 = (t < 255) ? s_sc[i  ][t+1] : 0.f;
        float l1 = (t > 0)   ? s_sc[i+1][t-1] : 0.f;
        float r1 = (t < 255) ? s_sc[i+1][t+1] : 0.f;
        float l2 = (t > 0)   ? s_sc[i+2][t-1] : 0.f;
        float r2 = (t < 255) ? s_sc[i+2][t+1] : 0.f;
        y[i] = bias
             + w00*l0 + w01*s_sc[i  ][t] + w02*r0
             + w10*l1 + w11*s_sc[i+1][t] + w12*r1
             + w20*l2 + w21*s_sc[i+2][t] + w22*r2;
    }

    int lane = t & 63, wv = t >> 6;

    // row max across 256 threads
    #pragma unroll
    for (int i = 0; i < TH; ++i) {
        float m = y[i];
        #pragma unroll
        for (int o = 32; o > 0; o >>= 1) m = fmaxf(m, __shfl_xor(m, o));
        if (lane == 0) red[i][wv] = m;
    }
    __syncthreads();
    float mx[TH];
    #pragma unroll
    for (int i = 0; i < TH; ++i)
        mx[i] = fmaxf(fmaxf(red[i][0], red[i][1]), fmaxf(red[i][2], red[i][3]));
    __syncthreads();   // red about to be reused

    // exp + row sum
    #pragma unroll
    for (int i = 0; i < TH; ++i) {
        float e = __expf(y[i] - mx[i]);
        s_at[i][t] = e;
        #pragma unroll
        for (int o = 32; o > 0; o >>= 1) e += __shfl_xor(e, o);
        if (lane == 0) red[i][wv] = e;
    }
    __syncthreads();
    float sm[TH];
    #pragma unroll
    for (int i = 0; i < TH; ++i)
        sm[i] = (red[i][0] + red[i][1]) + (red[i][2] + red[i][3]);

    // PV: out[h0+i][t] = (1/sm[i]) * sum_g s_at[i][g] * v[g][t]  + x
    float acc[TH];
    #pragma unroll
    for (int i = 0; i < TH; ++i) acc[i] = 0.f;

    for (int g = 0; g < 256; g += 4) {
        float v0 = vb[(g+0) * 256 + t];
        float v1 = vb[(g+1) * 256 + t];
        float v2 = vb[(g+2) * 256 + t];
        float v3 = vb[(g+3) * 256 + t];
        #pragma unroll
        for (int i = 0; i < TH; ++i) {
            float4 aa = *(const float4*)&s_at[i][g];
            acc[i] += aa.x * v0 + aa.y * v1 + aa.z * v2 + aa.w * v3;
        }
    }

    const float* xb = x + (size_t)bc * HW;
    float* ob = out + (size_t)bc * HW;
    #pragma unroll
    for (int i = 0; i < TH; ++i) {
        ob[(h0 + i) * 256 + t] = acc[i] / sm[i] + xb[(h0 + i) * 256 + t];
    }
}

// ---------------------------------------------------------------------------
extern "C" void kernel_launch(void* const* d_in, const int* in_sizes, int n_in,
                              void* d_out, int out_size, void* d_ws, size_t ws_size,
                              hipStream_t stream)
{
    const float* x     = (const float*)d_in[0];
    const float* w_qkv = (const float*)d_in[1];
    const float* b_qkv = (const float*)d_in[2];
    const float* w_dw  = (const float*)d_in[3];
    const float* b_dw  = (const float*)d_in[4];
    float* ws  = (float*)d_ws;   // needs 3*BCHW*4 = 201.3 MB
    float* out = (float*)d_out;

    qkv_kernel  <<<B * HW / 256, 256, 0, stream>>>(x, w_qkv, b_qkv, ws);
    scores_kernel<<<B * C * 4,   256, 0, stream>>>(ws);
    attn_kernel <<<B * C * 16,   256, 0, stream>>>(ws, w_dw, b_dw, x, out);
}

// Round 2
// 471.707 us; speedup vs baseline: 1.2774x; 1.2774x over previous
//
#include <hip/hip_runtime.h>
#include <math.h>

#define B 4
#define C 64
#define H 256
#define W 256
#define HW (H*W)            // 65536
#define CHW (C*HW)          // 4194304
#define BCHW (B*CHW)        // 16777216

typedef __attribute__((ext_vector_type(8))) short short8v;   // 8 bf16
typedef __attribute__((ext_vector_type(4))) float f32x4;

// ws byte layout (total 12*BCHW = 201.3 MB):
//   [0,            4*BCHW)   qpk u32 (bf16 hi | lo<<16)  -> overwritten by scores f32
//   [4*BCHW,       8*BCHW)   kpk u32
//   [8*BCHW,      10*BCHW)   v  bf16 [bc][h][w]
//   [10*BCHW,     12*BCHW)   vT bf16 [bc][w][h]

__device__ inline uint32_t f32_to_bf16(float f) {
    uint32_t u = __float_as_uint(f);
    return (u + 0x7fffu + ((u >> 16) & 1u)) >> 16;   // RNE
}
__device__ inline float bf16_to_f32(uint32_t h) { return __uint_as_float(h << 16); }

__device__ inline void unpack8(uint4 a, uint4 b, short8v& hi, short8v& lo) {
    union { uint32_t u[4]; short8v v; } Hh, Ll;
    Hh.u[0] = (a.x & 0xffffu) | (a.y << 16);
    Hh.u[1] = (a.z & 0xffffu) | (a.w << 16);
    Hh.u[2] = (b.x & 0xffffu) | (b.y << 16);
    Hh.u[3] = (b.z & 0xffffu) | (b.w << 16);
    Ll.u[0] = (a.x >> 16) | (a.y & 0xffff0000u);
    Ll.u[1] = (a.z >> 16) | (a.w & 0xffff0000u);
    Ll.u[2] = (b.x >> 16) | (b.y & 0xffff0000u);
    Ll.u[3] = (b.z >> 16) | (b.w & 0xffff0000u);
    hi = Hh.v; lo = Ll.v;
}

// ---------------------------------------------------------------------------
// K1: qkv 1x1 conv. q,k packed hi/lo u32; v bf16.
// ---------------------------------------------------------------------------
__global__ __launch_bounds__(256) void qkv_kernel(
    const float* __restrict__ x, const float* __restrict__ w,
    const float* __restrict__ bias, uint32_t* __restrict__ qpk,
    uint32_t* __restrict__ kpk, ushort* __restrict__ vbf)
{
    __shared__ float wl[192 * 64];
    __shared__ float bl[192];
    int t = threadIdx.x;
    for (int i = t; i < 192 * 64; i += 256) wl[i] = w[i];
    if (t < 192) bl[t] = bias[t];
    __syncthreads();

    int p = blockIdx.x * 256 + t;
    int b = p >> 16;
    int s = p & (HW - 1);

    const float* xp = x + (size_t)b * CHW + s;
    float xr[64];
    #pragma unroll
    for (int c = 0; c < 64; ++c) xr[c] = xp[(size_t)c * HW];

    for (int oc = 0; oc < 192; ++oc) {
        float acc = bl[oc];
        const float* wrow = &wl[oc * 64];
        #pragma unroll
        for (int c = 0; c < 64; ++c) acc += wrow[c] * xr[c];
        int grp = oc >> 6, cc = oc & 63;
        size_t idx = ((size_t)(b * 64 + cc)) * HW + s;
        if (grp == 2) {
            vbf[idx] = (ushort)f32_to_bf16(acc);
        } else {
            uint32_t hb = f32_to_bf16(acc);
            uint32_t lb = f32_to_bf16(acc - bf16_to_f32(hb));
            (grp == 0 ? qpk : kpk)[idx] = hb | (lb << 16);
        }
    }
}

// ---------------------------------------------------------------------------
// K1.5: transpose v -> vT (per bc, 64x64 tiles through LDS)
// ---------------------------------------------------------------------------
__global__ __launch_bounds__(256) void vt_kernel(
    const ushort* __restrict__ vbf, ushort* __restrict__ vt)
{
    __shared__ ushort tile[64][65];
    int t = threadIdx.x;
    int bc = blockIdx.x >> 4;
    int tj = blockIdx.x & 15;
    int h0 = (tj >> 2) * 64, w0 = (tj & 3) * 64;
    const ushort* vb = vbf + (size_t)bc * HW;
    ushort* vo = vt + (size_t)bc * HW;
    #pragma unroll
    for (int i = 0; i < 16; ++i) {
        int idx = t + 256 * i;
        int r = idx >> 6, c = idx & 63;
        tile[r][c] = vb[(h0 + r) * 256 + w0 + c];
    }
    __syncthreads();
    #pragma unroll
    for (int i = 0; i < 16; ++i) {
        int idx = t + 256 * i;
        int r = idx >> 6, c = idx & 63;
        vo[(w0 + r) * 256 + h0 + c] = tile[c][r];
    }
}

// ---------------------------------------------------------------------------
// K2: scores = Q*K^T via bf16 hi/lo split MFMA (3 products, fp32 accum).
// Block: (bc, 64 h-rows). 4 waves split g into 64-wide ranges.
// Epilogue overwrites qpk region with fp32 scores (after __syncthreads).
// ---------------------------------------------------------------------------
__global__ __launch_bounds__(256) void scores_kernel(uint32_t* __restrict__ ws)
{
    int t = threadIdx.x;
    int lane = t & 63, wv = t >> 6;
    int l15 = lane & 15, l4 = lane >> 4;
    int bc = blockIdx.x >> 2;
    int h0 = (blockIdx.x & 3) * 64;
    int g0 = wv * 64;

    const uint32_t* qb = ws + (size_t)bc * HW;
    const uint32_t* kb = ws + (size_t)BCHW + (size_t)bc * HW;

    f32x4 acc[4][4];
    #pragma unroll
    for (int i = 0; i < 4; ++i)
        #pragma unroll
        for (int j = 0; j < 4; ++j) acc[i][j] = (f32x4)0.f;

    for (int kc = 0; kc < 8; ++kc) {
        int ko = kc * 32 + l4 * 8;
        short8v bhi[4], blo[4];
        #pragma unroll
        for (int gf = 0; gf < 4; ++gf) {
            const uint32_t* p = &kb[(g0 + gf * 16 + l15) * 256 + ko];
            uint4 u0 = *(const uint4*)p;
            uint4 u1 = *(const uint4*)(p + 4);
            unpack8(u0, u1, bhi[gf], blo[gf]);
        }
        #pragma unroll
        for (int hf = 0; hf < 4; ++hf) {
            const uint32_t* p = &qb[(h0 + hf * 16 + l15) * 256 + ko];
            uint4 u0 = *(const uint4*)p;
            uint4 u1 = *(const uint4*)(p + 4);
            short8v ahi, alo;
            unpack8(u0, u1, ahi, alo);
            #pragma unroll
            for (int gf = 0; gf < 4; ++gf) {
                acc[hf][gf] = __builtin_amdgcn_mfma_f32_16x16x32_bf16(ahi, bhi[gf], acc[hf][gf], 0, 0, 0);
                acc[hf][gf] = __builtin_amdgcn_mfma_f32_16x16x32_bf16(ahi, blo[gf], acc[hf][gf], 0, 0, 0);
                acc[hf][gf] = __builtin_amdgcn_mfma_f32_16x16x32_bf16(alo, bhi[gf], acc[hf][gf], 0, 0, 0);
            }
        }
    }

    __syncthreads();   // all waves' q reads drained before overwriting with scores

    float* sb = (float*)qb;
    #pragma unroll
    for (int hf = 0; hf < 4; ++hf)
        #pragma unroll
        for (int gf = 0; gf < 4; ++gf)
            #pragma unroll
            for (int r = 0; r < 4; ++r) {
                int h = h0 + hf * 16 + l4 * 4 + r;
                int g = g0 + gf * 16 + l15;
                sb[h * 256 + g] = acc[hf][gf][r];
            }
}

// ---------------------------------------------------------------------------
// K3: conv3x3 + softmax + PV (bf16 MFMA) + residual.
// Block: (bc, 64 h-rows), 256 threads. Phase A: thread t = column g,
// rolling conv window, batched wave-shuffle softmax. attn -> swizzled LDS.
// Phase B: waves split w; A-frags from LDS, B-frags (vT) from global.
// ---------------------------------------------------------------------------
__global__ __launch_bounds__(256) void attn_kernel(
    const float* __restrict__ scores, const ushort* __restrict__ vt,
    const float* __restrict__ wdw, const float* __restrict__ bdw,
    const float* __restrict__ x, float* __restrict__ out)
{
    __shared__ ushort attn_s[64 * 256];   // 32 KB, 16B-chunk XOR swizzle per row
    __shared__ float red[64][4];
    __shared__ float mxf[64];
    __shared__ float smf[64];

    int t = threadIdx.x;
    int lane = t & 63, wv = t >> 6;
    int l15 = lane & 15, l4 = lane >> 4;
    int bc = blockIdx.x >> 2;
    int h0 = (blockIdx.x & 3) * 64;
    int c = bc & 63;

    const float* sb = scores + (size_t)bc * HW;
    const ushort* vb = vt + (size_t)bc * HW;
    const float* xb = x + (size_t)bc * HW;
    float* ob = out + (size_t)bc * HW;

    float w00 = wdw[c*9+0], w01 = wdw[c*9+1], w02 = wdw[c*9+2];
    float w10 = wdw[c*9+3], w11 = wdw[c*9+4], w12 = wdw[c*9+5];
    float w20 = wdw[c*9+6], w21 = wdw[c*9+7], w22 = wdw[c*9+8];
    float bias = bdw[c];

    // ---- Phase A: conv (rolling window) ----
    float y[64];
    float l0, m0, r0, l1, m1, r1, l2, m2, r2;
    {
        int h = h0 - 1;
        if (h >= 0) {
            const float* row = sb + h * 256;
            m0 = row[t]; l0 = (t > 0) ? row[t-1] : 0.f; r0 = (t < 255) ? row[t+1] : 0.f;
        } else { l0 = m0 = r0 = 0.f; }
        const float* row = sb + h0 * 256;
        m1 = row[t]; l1 = (t > 0) ? row[t-1] : 0.f; r1 = (t < 255) ? row[t+1] : 0.f;
    }
    #pragma unroll
    for (int i = 0; i < 64; ++i) {
        int h = h0 + i + 1;
        if (h < 256) {
            const float* row = sb + h * 256;
            m2 = row[t]; l2 = (t > 0) ? row[t-1] : 0.f; r2 = (t < 255) ? row[t+1] : 0.f;
        } else { l2 = m2 = r2 = 0.f; }
        y[i] = bias
             + w00*l0 + w01*m0 + w02*r0
             + w10*l1 + w11*m1 + w12*r1
             + w20*l2 + w21*m2 + w22*r2;
        l0 = l1; m0 = m1; r0 = r1;
        l1 = l2; m1 = m2; r1 = r2;
    }

    // ---- softmax: row max ----
    #pragma unroll
    for (int i = 0; i < 64; ++i) {
        float m = y[i];
        #pragma unroll
        for (int o = 32; o > 0; o >>= 1) m = fmaxf(m, __shfl_xor(m, o));
        if (lane == 0) red[i][wv] = m;
    }
    __syncthreads();
    if (t < 64) {
        float4 r4 = *(const float4*)red[t];
        mxf[t] = fmaxf(fmaxf(r4.x, r4.y), fmaxf(r4.z, r4.w));
    }
    __syncthreads();

    // ---- exp, store bf16 attn (swizzled), row sum ----
    int chunk = t >> 3, within = t & 7;
    #pragma unroll
    for (int i = 0; i < 64; ++i) {
        float e = __expf(y[i] - mxf[i]);
        attn_s[i * 256 + ((chunk ^ (i & 7)) << 3) + within] = (ushort)f32_to_bf16(e);
        #pragma unroll
        for (int o = 32; o > 0; o >>= 1) e += __shfl_xor(e, o);
        if (lane == 0) red[i][wv] = e;
    }
    __syncthreads();
    if (t < 64) {
        float4 r4 = *(const float4*)red[t];
        smf[t] = 1.0f / ((r4.x + r4.y) + (r4.z + r4.w));
    }
    __syncthreads();

    // ---- Phase B: PV via MFMA. wave wv owns w-range [wv*64, wv*64+64) ----
    int w0 = wv * 64;
    f32x4 acc[4][4];   // [hf][wf]
    #pragma unroll
    for (int i = 0; i < 4; ++i)
        #pragma unroll
        for (int j = 0; j < 4; ++j) acc[i][j] = (f32x4)0.f;

    for (int kc = 0; kc < 8; ++kc) {
        short8v bfr[4];
        #pragma unroll
        for (int wf = 0; wf < 4; ++wf) {
            const ushort* p = vb + (size_t)(w0 + wf * 16 + l15) * 256 + kc * 32 + l4 * 8;
            bfr[wf] = *(const short8v*)p;
        }
        #pragma unroll
        for (int hf = 0; hf < 4; ++hf) {
            int row = hf * 16 + l15;
            int cbase = kc * 4 + l4;
            const ushort* ap = &attn_s[row * 256 + ((cbase ^ (row & 7)) << 3)];
            short8v afr = *(const short8v*)ap;
            #pragma unroll
            for (int wf = 0; wf < 4; ++wf)
                acc[hf][wf] = __builtin_amdgcn_mfma_f32_16x16x32_bf16(afr, bfr[wf], acc[hf][wf], 0, 0, 0);
        }
    }

    // ---- epilogue: scale by 1/sum, add residual ----
    #pragma unroll
    for (int hf = 0; hf < 4; ++hf)
        #pragma unroll
        for (int r = 0; r < 4; ++r) {
            int row = hf * 16 + l4 * 4 + r;
            float inv = smf[row];
            int hg = h0 + row;
            #pragma unroll
            for (int wf = 0; wf < 4; ++wf) {
                int wc = w0 + wf * 16 + l15;
                ob[hg * 256 + wc] = acc[hf][wf][r] * inv + xb[hg * 256 + wc];
            }
        }
}

// ---------------------------------------------------------------------------
extern "C" void kernel_launch(void* const* d_in, const int* in_sizes, int n_in,
                              void* d_out, int out_size, void* d_ws, size_t ws_size,
                              hipStream_t stream)
{
    const float* x     = (const float*)d_in[0];
    const float* w_qkv = (const float*)d_in[1];
    const float* b_qkv = (const float*)d_in[2];
    const float* w_dw  = (const float*)d_in[3];
    const float* b_dw  = (const float*)d_in[4];

    uint32_t* qpk = (uint32_t*)d_ws;
    uint32_t* kpk = qpk + (size_t)BCHW;
    ushort*   vbf = (ushort*)(qpk + (size_t)2 * BCHW);
    ushort*   vtp = vbf + (size_t)BCHW;
    float*    out = (float*)d_out;

    qkv_kernel   <<<B * HW / 256, 256, 0, stream>>>(x, w_qkv, b_qkv, qpk, kpk, vbf);
    vt_kernel    <<<B * C * 16,   256, 0, stream>>>(vbf, vtp);
    scores_kernel<<<B * C * 4,    256, 0, stream>>>(qpk);
    attn_kernel  <<<B * C * 4,    256, 0, stream>>>((const float*)qpk, vtp, w_dw, b_dw, x, out);
}